// Round 10
// baseline (202.371 us; speedup 1.0000x reference)
//
#include <hip/hip_runtime.h>
#include <hip/hip_bf16.h>

// MultiHeadAttention: B=4, S=2048, D_MODEL=512, N_HEAD=8, D_K=64
// Pipeline: proj3 (Q*log2e/8, K, V->transposed fused), flash_attn (4-wave LDS-staged, 2 blocks/CU), out_gemm

typedef __attribute__((ext_vector_type(8))) short short8;
typedef __attribute__((ext_vector_type(4))) float f32x4;
typedef __attribute__((ext_vector_type(16))) float f32x16;
typedef __attribute__((ext_vector_type(4))) unsigned short u16x4;

static __device__ __forceinline__ unsigned short f2bf(float x) {
  union { float f; unsigned u; } v; v.f = x;
  unsigned r = v.u + 0x7fffu + ((v.u >> 16) & 1u);  // round-to-nearest-even
  return (unsigned short)(r >> 16);
}

static __device__ __forceinline__ short8 ld8(const unsigned short* p) {
  return *reinterpret_cast<const short8*>(p);
}

static __device__ __forceinline__ float vmax3(float a, float b, float c) {
  float r; asm("v_max3_f32 %0, %1, %2, %3" : "=v"(r) : "v"(a), "v"(b), "v"(c)); return r;
}

static __device__ __forceinline__ float vexp2(float x) {
  float r; asm("v_exp_f32 %0, %1" : "=v"(r) : "v"(x)); return r;
}

static __device__ __forceinline__ int cvtpk(float a, float b) {
  int r; asm("v_cvt_pk_bf16_f32 %0, %1, %2" : "=v"(r) : "v"(a), "v"(b)); return r;
}

// ---------------------------------------------------------------------------
// Fused projection GEMMs: z = blockIdx.z selects {Q, K, V}.
// Q gets oscale = (1/8)*log2(e) so flash softmax uses exp2 directly.
// V (z==2) written transposed [b*8+h][d][s].
// ---------------------------------------------------------------------------
__global__ __launch_bounds__(256) void proj3(
    const float* __restrict__ Xq, const float* __restrict__ Xk, const float* __restrict__ Xv,
    const float* __restrict__ Wq, const float* __restrict__ Wk, const float* __restrict__ Wv,
    const float* __restrict__ bq, const float* __restrict__ bk, const float* __restrict__ bv,
    unsigned short* __restrict__ Qh, unsigned short* __restrict__ Kh,
    unsigned short* __restrict__ Vt)
{
  const int z = blockIdx.z;
  const float* X = z == 0 ? Xq : z == 1 ? Xk : Xv;
  const float* W = z == 0 ? Wq : z == 1 ? Wk : Wv;
  const float* bias = z == 0 ? bq : z == 1 ? bk : bv;
  unsigned short* dst = z == 0 ? Qh : z == 1 ? Kh : Vt;
  const int vmode = (z == 2);
  const float oscale = z == 0 ? 0.1803368801f : 1.0f;  // (1/8)*log2(e)

  __shared__ unsigned short Al[128][40];
  __shared__ unsigned short Bl[128][40];
  const int tid = threadIdx.x;
  const int lane = tid & 63;
  const int g = lane >> 4, c = lane & 15;
  const int wave = tid >> 6;
  const int m0 = blockIdx.x * 128, n0 = blockIdx.y * 128;
  const int wm = (wave & 1) * 64, wn = (wave >> 1) * 64;
  f32x4 acc[4][4] = {};

  const int srow = tid >> 3;
  const int scol = (tid & 7) * 4;

  for (int k0 = 0; k0 < 512; k0 += 32) {
    __syncthreads();
#pragma unroll
    for (int p = 0; p < 4; ++p) {
      int row = p * 32 + srow;
      f32x4 xv = *reinterpret_cast<const f32x4*>(&X[(size_t)(m0 + row) * 512 + k0 + scol]);
      u16x4 xb = { f2bf(xv[0]), f2bf(xv[1]), f2bf(xv[2]), f2bf(xv[3]) };
      *reinterpret_cast<u16x4*>(&Al[row][scol]) = xb;
      f32x4 wv = *reinterpret_cast<const f32x4*>(&W[(size_t)(n0 + row) * 512 + k0 + scol]);
      u16x4 wb = { f2bf(wv[0]), f2bf(wv[1]), f2bf(wv[2]), f2bf(wv[3]) };
      *reinterpret_cast<u16x4*>(&Bl[row][scol]) = wb;
    }
    __syncthreads();
    short8 af[4], bfr[4];
#pragma unroll
    for (int i = 0; i < 4; ++i) {
      af[i]  = ld8(&Al[wm + i * 16 + c][g * 8]);
      bfr[i] = ld8(&Bl[wn + i * 16 + c][g * 8]);
    }
#pragma unroll
    for (int i = 0; i < 4; ++i)
#pragma unroll
      for (int j = 0; j < 4; ++j)
        acc[i][j] = __builtin_amdgcn_mfma_f32_16x16x32_bf16(af[i], bfr[j], acc[i][j], 0, 0, 0);
  }

#pragma unroll
  for (int j = 0; j < 4; ++j) {
    int col = n0 + wn + j * 16 + c;
    float bcol = bias[col];
    int h = col >> 6, d = col & 63;
#pragma unroll
    for (int i = 0; i < 4; ++i) {
#pragma unroll
      for (int r = 0; r < 4; ++r) {
        int row = m0 + wm + i * 16 + g * 4 + r;
        int b = row >> 11, s = row & 2047;
        float val = (acc[i][j][r] + bcol) * oscale;
        size_t idx = vmode ? ((size_t)((b * 8 + h) * 64 + d) * 2048 + s)
                           : ((size_t)((b * 8 + h) * 2048 + s) * 64 + d);
        dst[idx] = f2bf(val);
      }
    }
  }
}

// ---------------------------------------------------------------------------
// Flash attention, 4-wave LDS-staged, 2 blocks/CU (occupancy lever vs r9's
// 8-wave 1-block/CU), swapped-QK 32x32, shfl-free P repack, XCD-pinned heads.
// Block = 4 waves x 32 q-rows = 128 q; grid = 512 blocks (16 qtiles x 32 bh),
// class c = n&7 (HW XCD round-robin) serves heads 4c..4c+3 (K/V L2-resident).
// K/V staged in double-buffered LDS (padded [64][68]: 2-way banks = free),
// T14 async-split: global loads (2 K + 2 V short8/thread) issued one full
// compute phase early; ds_write after compute; ONE barrier per tile.
// K A-frag rows pre-permuted (blq = swap bits 2<->3) so cvt_pk output IS the
// PV B-fragment (no cross-lane repack). No split-KV: no merge.
// ---------------------------------------------------------------------------
__global__ __launch_bounds__(256) void flash_attn(
    const unsigned short* __restrict__ Qh, const unsigned short* __restrict__ Kh,
    const unsigned short* __restrict__ Vt, unsigned short* __restrict__ attn)
{
  __shared__ unsigned short Kl[2][64][68];
  __shared__ unsigned short Vl[2][64][68];
  const int tid = threadIdx.x;
  const int lane = tid & 63;
  const int wave = tid >> 6;          // 0..3
  const int lq = lane & 31;           // q column / frag row
  const int hi = lane >> 5;           // lane half
  const int n = blockIdx.x;           // 0..511
  const int cls = n & 7;              // XCD class
  const int idx = n >> 3;             // 0..63
  const int bh = cls * 4 + (idx & 3); // XCD-pinned head
  const int q0 = (idx >> 2) * 128 + wave * 32;
  const unsigned short* Qp = Qh + (size_t)bh * 2048 * 64;
  const unsigned short* Kp = Kh + (size_t)bh * 2048 * 64;
  const unsigned short* Vp = Vt + (size_t)bh * 64 * 2048;
  const int blq = (lq & 19) | ((lq & 4) << 1) | ((lq & 8) >> 1);  // swap bits 2,3

  // staging mapping: 256 threads cover one [64][64] bf16 tile, 32B each
  const int srow = tid >> 2;          // 0..63
  const int scol = (tid & 3) * 16;    // 0,16,32,48

  // Q B-fragments: col=lq, k=d = ds*16 + hi*8 + j
  short8 qf[4];
#pragma unroll
  for (int ds = 0; ds < 4; ++ds)
    qf[ds] = ld8(Qp + (size_t)(q0 + lq) * 64 + ds * 16 + hi * 8);

  f32x16 acc0 = {}, acc1 = {};
  float mrun = -1e30f, lrun = 0.f;    // lrun = OWN-HALF partial sum

  // ---- prologue: stage tile 0, prefetch tile 1 into regs ----
  short8 ks0 = ld8(Kp + (size_t)srow * 64 + scol);
  short8 ks1 = ld8(Kp + (size_t)srow * 64 + scol + 8);
  short8 vs0 = ld8(Vp + (size_t)srow * 2048 + scol);
  short8 vs1 = ld8(Vp + (size_t)srow * 2048 + scol + 8);
  *reinterpret_cast<short8*>(&Kl[0][srow][scol]) = ks0;
  *reinterpret_cast<short8*>(&Kl[0][srow][scol + 8]) = ks1;
  *reinterpret_cast<short8*>(&Vl[0][srow][scol]) = vs0;
  *reinterpret_cast<short8*>(&Vl[0][srow][scol + 8]) = vs1;
  ks0 = ld8(Kp + (size_t)(64 + srow) * 64 + scol);
  ks1 = ld8(Kp + (size_t)(64 + srow) * 64 + scol + 8);
  vs0 = ld8(Vp + (size_t)srow * 2048 + 64 + scol);
  vs1 = ld8(Vp + (size_t)srow * 2048 + 64 + scol + 8);
  __syncthreads();

  for (int t = 0; t < 32; ++t) {
    const int cur = t & 1;

    // ---- K frags from LDS (rows blq / 32+blq pre-permuted) ----
    short8 kf0 = ld8(&Kl[cur][blq][ 0 + hi * 8]);
    short8 kf1 = ld8(&Kl[cur][blq][16 + hi * 8]);
    short8 kf2 = ld8(&Kl[cur][blq][32 + hi * 8]);
    short8 kf3 = ld8(&Kl[cur][blq][48 + hi * 8]);
    short8 kf4 = ld8(&Kl[cur][32 + blq][ 0 + hi * 8]);
    short8 kf5 = ld8(&Kl[cur][32 + blq][16 + hi * 8]);
    short8 kf6 = ld8(&Kl[cur][32 + blq][32 + hi * 8]);
    short8 kf7 = ld8(&Kl[cur][32 + blq][48 + hi * 8]);

    // ---- QK^T: two independent 32-kv chains ----
    f32x16 sp0 = {}, sp1 = {};
    __builtin_amdgcn_s_setprio(1);
    sp0 = __builtin_amdgcn_mfma_f32_32x32x16_bf16(kf0, qf[0], sp0, 0, 0, 0);
    sp1 = __builtin_amdgcn_mfma_f32_32x32x16_bf16(kf4, qf[0], sp1, 0, 0, 0);
    sp0 = __builtin_amdgcn_mfma_f32_32x32x16_bf16(kf1, qf[1], sp0, 0, 0, 0);
    sp1 = __builtin_amdgcn_mfma_f32_32x32x16_bf16(kf5, qf[1], sp1, 0, 0, 0);
    sp0 = __builtin_amdgcn_mfma_f32_32x32x16_bf16(kf2, qf[2], sp0, 0, 0, 0);
    sp1 = __builtin_amdgcn_mfma_f32_32x32x16_bf16(kf6, qf[2], sp1, 0, 0, 0);
    sp0 = __builtin_amdgcn_mfma_f32_32x32x16_bf16(kf3, qf[3], sp0, 0, 0, 0);
    sp1 = __builtin_amdgcn_mfma_f32_32x32x16_bf16(kf7, qf[3], sp1, 0, 0, 0);
    __builtin_amdgcn_s_setprio(0);

    // ---- V frags from LDS (independent of softmax; latency hidden under it) ----
    short8 vf0 = ld8(&Vl[cur][lq][ 0 + hi * 8]);
    short8 vf1 = ld8(&Vl[cur][32 + lq][ 0 + hi * 8]);
    short8 vf2 = ld8(&Vl[cur][lq][16 + hi * 8]);
    short8 vf3 = ld8(&Vl[cur][32 + lq][16 + hi * 8]);
    short8 vf4 = ld8(&Vl[cur][lq][32 + hi * 8]);
    short8 vf5 = ld8(&Vl[cur][32 + lq][32 + hi * 8]);
    short8 vf6 = ld8(&Vl[cur][lq][48 + hi * 8]);
    short8 vf7 = ld8(&Vl[cur][32 + lq][48 + hi * 8]);

    // ---- online softmax (log2 domain) over 32 lane-local scores ----
    float ta = vmax3(sp0[0], sp0[1], sp0[2]);
    float tb = vmax3(sp0[3], sp0[4], sp0[5]);
    float tc = vmax3(sp0[6], sp0[7], sp0[8]);
    float td = vmax3(sp0[9], sp0[10], sp0[11]);
    ta = vmax3(ta, sp0[12], sp0[13]);
    tb = vmax3(tb, sp0[14], sp0[15]);
    tc = vmax3(tc, sp1[0], sp1[1]);
    td = vmax3(td, sp1[2], sp1[3]);
    ta = vmax3(ta, sp1[4], sp1[5]);
    tb = vmax3(tb, sp1[6], sp1[7]);
    tc = vmax3(tc, sp1[8], sp1[9]);
    td = vmax3(td, sp1[10], sp1[11]);
    ta = vmax3(ta, sp1[12], sp1[13]);
    tb = vmax3(tb, sp1[14], sp1[15]);
    float tm = fmaxf(vmax3(ta, tb, tc), td);
    float tmx = fmaxf(tm, __shfl_xor(tm, 32));
    if (!__all(tmx <= mrun + 11.0f)) {   // defer-max: P bounded by 2^11
      float mn = fmaxf(mrun, tmx);
      float alpha = vexp2(mrun - mn);    // uniform across both halves
      mrun = mn;
      lrun *= alpha;
#pragma unroll
      for (int i = 0; i < 16; ++i) { acc0[i] *= alpha; acc1[i] *= alpha; }
    }
    float p0[16], p1[16];
    float s0 = 0.f, s1 = 0.f, s2 = 0.f, s3 = 0.f;
    float s4 = 0.f, s5 = 0.f, s6 = 0.f, s7 = 0.f;
#pragma unroll
    for (int i = 0; i < 4; ++i) {
      p0[4 * i]     = vexp2(sp0[4 * i]     - mrun); s0 += p0[4 * i];
      p0[4 * i + 1] = vexp2(sp0[4 * i + 1] - mrun); s1 += p0[4 * i + 1];
      p0[4 * i + 2] = vexp2(sp0[4 * i + 2] - mrun); s2 += p0[4 * i + 2];
      p0[4 * i + 3] = vexp2(sp0[4 * i + 3] - mrun); s3 += p0[4 * i + 3];
      p1[4 * i]     = vexp2(sp1[4 * i]     - mrun); s4 += p1[4 * i];
      p1[4 * i + 1] = vexp2(sp1[4 * i + 1] - mrun); s5 += p1[4 * i + 1];
      p1[4 * i + 2] = vexp2(sp1[4 * i + 2] - mrun); s6 += p1[4 * i + 2];
      p1[4 * i + 3] = vexp2(sp1[4 * i + 3] - mrun); s7 += p1[4 * i + 3];
    }
    lrun += ((s0 + s1) + (s2 + s3)) + ((s4 + s5) + (s6 + s7));

    // ---- P -> bf16 B-fragments, NO cross-lane ops (K rows pre-permuted) ----
    union { int w[4]; short8 v; } pf0, pf1, pf2, pf3;
#pragma unroll
    for (int w = 0; w < 4; ++w) {
      pf0.w[w] = cvtpk(p0[2 * w],     p0[2 * w + 1]);
      pf1.w[w] = cvtpk(p0[8 + 2 * w], p0[9 + 2 * w]);
      pf2.w[w] = cvtpk(p1[2 * w],     p1[2 * w + 1]);
      pf3.w[w] = cvtpk(p1[8 + 2 * w], p1[9 + 2 * w]);
    }

    // ---- PV: O^T[d][q] += V^T x P, two independent d-chains ----
    __builtin_amdgcn_s_setprio(1);
    acc0 = __builtin_amdgcn_mfma_f32_32x32x16_bf16(vf0, pf0.v, acc0, 0, 0, 0);
    acc1 = __builtin_amdgcn_mfma_f32_32x32x16_bf16(vf1, pf0.v, acc1, 0, 0, 0);
    acc0 = __builtin_amdgcn_mfma_f32_32x32x16_bf16(vf2, pf1.v, acc0, 0, 0, 0);
    acc1 = __builtin_amdgcn_mfma_f32_32x32x16_bf16(vf3, pf1.v, acc1, 0, 0, 0);
    acc0 = __builtin_amdgcn_mfma_f32_32x32x16_bf16(vf4, pf2.v, acc0, 0, 0, 0);
    acc1 = __builtin_amdgcn_mfma_f32_32x32x16_bf16(vf5, pf2.v, acc1, 0, 0, 0);
    acc0 = __builtin_amdgcn_mfma_f32_32x32x16_bf16(vf6, pf3.v, acc0, 0, 0, 0);
    acc1 = __builtin_amdgcn_mfma_f32_32x32x16_bf16(vf7, pf3.v, acc1, 0, 0, 0);
    __builtin_amdgcn_s_setprio(0);

    // ---- T14 write-late stage + single barrier; issue-early next loads ----
    if (t < 31) {
      *reinterpret_cast<short8*>(&Kl[cur ^ 1][srow][scol]) = ks0;
      *reinterpret_cast<short8*>(&Kl[cur ^ 1][srow][scol + 8]) = ks1;
      *reinterpret_cast<short8*>(&Vl[cur ^ 1][srow][scol]) = vs0;
      *reinterpret_cast<short8*>(&Vl[cur ^ 1][srow][scol + 8]) = vs1;
      __syncthreads();
      if (t < 30) {
        ks0 = ld8(Kp + (size_t)((t + 2) * 64 + srow) * 64 + scol);
        ks1 = ld8(Kp + (size_t)((t + 2) * 64 + srow) * 64 + scol + 8);
        vs0 = ld8(Vp + (size_t)srow * 2048 + (t + 2) * 64 + scol);
        vs1 = ld8(Vp + (size_t)srow * 2048 + (t + 2) * 64 + scol + 8);
      }
    }
  }

  // ---- epilogue: deferred cross-half l-sum, direct write (no merge) ----
  float lfull = lrun + __shfl_xor(lrun, 32);
  float rl = 1.0f / lfull;
  const int b = bh >> 3, h = bh & 7;
  unsigned short* base = attn + ((size_t)(b * 2048 + q0 + lq)) * 512 + h * 64;
#pragma unroll
  for (int g = 0; g < 4; ++g) {
    u16x4 oa, ob;
#pragma unroll
    for (int j = 0; j < 4; ++j) {
      oa[j] = f2bf(acc0[4 * g + j] * rl);
      ob[j] = f2bf(acc1[4 * g + j] * rl);
    }
    *reinterpret_cast<u16x4*>(base + 8 * g + 4 * hi) = oa;
    *reinterpret_cast<u16x4*>(base + 32 + 8 * g + 4 * hi) = ob;
  }
}

// ---------------------------------------------------------------------------
// Output projection: out(fp32) = attn(bf16)[8192,512] @ W_o^T + b_o
// ---------------------------------------------------------------------------
__global__ __launch_bounds__(256) void out_gemm(
    const unsigned short* __restrict__ A, const float* __restrict__ W,
    const float* __restrict__ bias, float* __restrict__ out)
{
  __shared__ unsigned short Al[128][40];
  __shared__ unsigned short Bl[128][40];
  const int tid = threadIdx.x;
  const int lane = tid & 63;
  const int g = lane >> 4, c = lane & 15;
  const int wave = tid >> 6;
  const int m0 = blockIdx.x * 128, n0 = blockIdx.y * 128;
  const int wm = (wave & 1) * 64, wn = (wave >> 1) * 64;
  f32x4 acc[4][4] = {};

  const int arow = tid >> 2;
  const int acol = (tid & 3) * 8;
  const int srow = tid >> 3;
  const int scol = (tid & 7) * 4;

  for (int k0 = 0; k0 < 512; k0 += 32) {
    __syncthreads();
#pragma unroll
    for (int p = 0; p < 2; ++p) {
      int row = p * 64 + arow;
      short8 av = ld8(&A[(size_t)(m0 + row) * 512 + k0 + acol]);
      *reinterpret_cast<short8*>(&Al[row][acol]) = av;
    }
#pragma unroll
    for (int p = 0; p < 4; ++p) {
      int row = p * 32 + srow;
      f32x4 wv = *reinterpret_cast<const f32x4*>(&W[(size_t)(n0 + row) * 512 + k0 + scol]);
      u16x4 wb = { f2bf(wv[0]), f2bf(wv[1]), f2bf(wv[2]), f2bf(wv[3]) };
      *reinterpret_cast<u16x4*>(&Bl[row][scol]) = wb;
    }
    __syncthreads();
    short8 af[4], bfr[4];
#pragma unroll
    for (int i = 0; i < 4; ++i) {
      af[i]  = ld8(&Al[wm + i * 16 + c][g * 8]);
      bfr[i] = ld8(&Bl[wn + i * 16 + c][g * 8]);
    }
#pragma unroll
    for (int i = 0; i < 4; ++i)
#pragma unroll
      for (int j = 0; j < 4; ++j)
        acc[i][j] = __builtin_amdgcn_mfma_f32_16x16x32_bf16(af[i], bfr[j], acc[i][j], 0, 0, 0);
  }

#pragma unroll
  for (int j = 0; j < 4; ++j) {
    int col = n0 + wn + j * 16 + c;
    float bcol = bias[col];
#pragma unroll
    for (int i = 0; i < 4; ++i)
#pragma unroll
      for (int r = 0; r < 4; ++r) {
        int row = m0 + wm + i * 16 + g * 4 + r;
        out[(size_t)row * 512 + col] = acc[i][j][r] + bcol;
      }
  }
}

extern "C" void kernel_launch(void* const* d_in, const int* in_sizes, int n_in,
                              void* d_out, int out_size, void* d_ws, size_t ws_size,
                              hipStream_t stream)
{
  const float* q  = (const float*)d_in[0];
  const float* k  = (const float*)d_in[1];
  const float* v  = (const float*)d_in[2];
  const float* Wq = (const float*)d_in[3];
  const float* bq = (const float*)d_in[4];
  const float* Wk = (const float*)d_in[5];
  const float* bk = (const float*)d_in[6];
  const float* Wv = (const float*)d_in[7];
  const float* bv = (const float*)d_in[8];
  const float* Wo = (const float*)d_in[9];
  const float* bo = (const float*)d_in[10];
  float* out = (float*)d_out;

  unsigned short* ws = (unsigned short*)d_ws;
  unsigned short* Qh = ws;                              // [32][2048][64] (pre-scaled log2e/8)
  unsigned short* Kh = ws + (size_t)4 * 1024 * 1024;    // [32][2048][64]
  unsigned short* Vt = ws + (size_t)8 * 1024 * 1024;    // [32][64][2048]
  unsigned short* at = ws + (size_t)12 * 1024 * 1024;   // [4][2048][512]

  dim3 blk(256);
  proj3<<<dim3(64, 4, 3), blk, 0, stream>>>(q, k, v, Wq, Wk, Wv, bq, bk, bv, Qh, Kh, Vt);
  flash_attn<<<dim3(512), dim3(256), 0, stream>>>(Qh, Kh, Vt, at);
  out_gemm<<<dim3(64, 4), blk, 0, stream>>>(at, Wo, bo, out);
}

// Round 11
// 198.440 us; speedup vs baseline: 1.0198x; 1.0198x over previous
//
#include <hip/hip_runtime.h>
#include <hip/hip_bf16.h>

// MultiHeadAttention: B=4, S=2048, D_MODEL=512, N_HEAD=8, D_K=64
// Pipeline: proj3 (Q*log2e/8, K, V->transposed fused), flash_attn (8-wave LDS-staged,
// VGPR-unconstrained via launch_bounds(512,2)), out_gemm

typedef __attribute__((ext_vector_type(8))) short short8;
typedef __attribute__((ext_vector_type(4))) float f32x4;
typedef __attribute__((ext_vector_type(16))) float f32x16;
typedef __attribute__((ext_vector_type(4))) unsigned short u16x4;

static __device__ __forceinline__ unsigned short f2bf(float x) {
  union { float f; unsigned u; } v; v.f = x;
  unsigned r = v.u + 0x7fffu + ((v.u >> 16) & 1u);  // round-to-nearest-even
  return (unsigned short)(r >> 16);
}

static __device__ __forceinline__ short8 ld8(const unsigned short* p) {
  return *reinterpret_cast<const short8*>(p);
}

static __device__ __forceinline__ float vmax3(float a, float b, float c) {
  float r; asm("v_max3_f32 %0, %1, %2, %3" : "=v"(r) : "v"(a), "v"(b), "v"(c)); return r;
}

static __device__ __forceinline__ float vexp2(float x) {
  float r; asm("v_exp_f32 %0, %1" : "=v"(r) : "v"(x)); return r;
}

static __device__ __forceinline__ int cvtpk(float a, float b) {
  int r; asm("v_cvt_pk_bf16_f32 %0, %1, %2" : "=v"(r) : "v"(a), "v"(b)); return r;
}

// ---------------------------------------------------------------------------
// Fused projection GEMMs: z = blockIdx.z selects {Q, K, V}.
// Q gets oscale = (1/8)*log2(e) so flash softmax uses exp2 directly.
// V (z==2) written transposed [b*8+h][d][s].
// ---------------------------------------------------------------------------
__global__ __launch_bounds__(256) void proj3(
    const float* __restrict__ Xq, const float* __restrict__ Xk, const float* __restrict__ Xv,
    const float* __restrict__ Wq, const float* __restrict__ Wk, const float* __restrict__ Wv,
    const float* __restrict__ bq, const float* __restrict__ bk, const float* __restrict__ bv,
    unsigned short* __restrict__ Qh, unsigned short* __restrict__ Kh,
    unsigned short* __restrict__ Vt)
{
  const int z = blockIdx.z;
  const float* X = z == 0 ? Xq : z == 1 ? Xk : Xv;
  const float* W = z == 0 ? Wq : z == 1 ? Wk : Wv;
  const float* bias = z == 0 ? bq : z == 1 ? bk : bv;
  unsigned short* dst = z == 0 ? Qh : z == 1 ? Kh : Vt;
  const int vmode = (z == 2);
  const float oscale = z == 0 ? 0.1803368801f : 1.0f;  // (1/8)*log2(e)

  __shared__ unsigned short Al[128][40];
  __shared__ unsigned short Bl[128][40];
  const int tid = threadIdx.x;
  const int lane = tid & 63;
  const int g = lane >> 4, c = lane & 15;
  const int wave = tid >> 6;
  const int m0 = blockIdx.x * 128, n0 = blockIdx.y * 128;
  const int wm = (wave & 1) * 64, wn = (wave >> 1) * 64;
  f32x4 acc[4][4] = {};

  const int srow = tid >> 3;
  const int scol = (tid & 7) * 4;

  for (int k0 = 0; k0 < 512; k0 += 32) {
    __syncthreads();
#pragma unroll
    for (int p = 0; p < 4; ++p) {
      int row = p * 32 + srow;
      f32x4 xv = *reinterpret_cast<const f32x4*>(&X[(size_t)(m0 + row) * 512 + k0 + scol]);
      u16x4 xb = { f2bf(xv[0]), f2bf(xv[1]), f2bf(xv[2]), f2bf(xv[3]) };
      *reinterpret_cast<u16x4*>(&Al[row][scol]) = xb;
      f32x4 wv = *reinterpret_cast<const f32x4*>(&W[(size_t)(n0 + row) * 512 + k0 + scol]);
      u16x4 wb = { f2bf(wv[0]), f2bf(wv[1]), f2bf(wv[2]), f2bf(wv[3]) };
      *reinterpret_cast<u16x4*>(&Bl[row][scol]) = wb;
    }
    __syncthreads();
    short8 af[4], bfr[4];
#pragma unroll
    for (int i = 0; i < 4; ++i) {
      af[i]  = ld8(&Al[wm + i * 16 + c][g * 8]);
      bfr[i] = ld8(&Bl[wn + i * 16 + c][g * 8]);
    }
#pragma unroll
    for (int i = 0; i < 4; ++i)
#pragma unroll
      for (int j = 0; j < 4; ++j)
        acc[i][j] = __builtin_amdgcn_mfma_f32_16x16x32_bf16(af[i], bfr[j], acc[i][j], 0, 0, 0);
  }

#pragma unroll
  for (int j = 0; j < 4; ++j) {
    int col = n0 + wn + j * 16 + c;
    float bcol = bias[col];
    int h = col >> 6, d = col & 63;
#pragma unroll
    for (int i = 0; i < 4; ++i) {
#pragma unroll
      for (int r = 0; r < 4; ++r) {
        int row = m0 + wm + i * 16 + g * 4 + r;
        int b = row >> 11, s = row & 2047;
        float val = (acc[i][j][r] + bcol) * oscale;
        size_t idx = vmode ? ((size_t)((b * 8 + h) * 64 + d) * 2048 + s)
                           : ((size_t)((b * 8 + h) * 2048 + s) * 64 + d);
        dst[idx] = f2bf(val);
      }
    }
  }
}

// ---------------------------------------------------------------------------
// Flash attention, 8-wave LDS-staged, swapped-QK 32x32, shfl-free P repack,
// XCD-pinned heads. IDENTICAL to round-9 version except __launch_bounds__(512,2):
// grid supplies only 2 waves/SIMD anyway, so cap occupancy at 2 and give the
// register allocator 256 VGPR -- lets all 16 K/V fragments + softmax state
// stay live so the 16 ds_reads batch ahead of the MFMA clusters instead of
// serializing load->use at ~120 cyc each (the r4-r10 130 us plateau).
// ---------------------------------------------------------------------------
__global__ __launch_bounds__(512, 2) void flash_attn(
    const unsigned short* __restrict__ Qh, const unsigned short* __restrict__ Kh,
    const unsigned short* __restrict__ Vt, unsigned short* __restrict__ attn)
{
  __shared__ unsigned short Kl[2][64][68];
  __shared__ unsigned short Vl[2][64][68];
  const int tid = threadIdx.x;
  const int lane = tid & 63;
  const int wave = tid >> 6;          // 0..7
  const int lq = lane & 31;           // q column / frag row
  const int hi = lane >> 5;           // lane half
  const int n = blockIdx.x;           // 0..255
  const int cls = n & 7;              // XCD class
  const int idx = n >> 3;             // 0..31
  const int bh = cls * 4 + (idx & 3); // XCD-pinned head
  const int q0 = (idx >> 2) * 256 + wave * 32;
  const unsigned short* Qp = Qh + (size_t)bh * 2048 * 64;
  const unsigned short* Kp = Kh + (size_t)bh * 2048 * 64;
  const unsigned short* Vp = Vt + (size_t)bh * 64 * 2048;
  const int blq = (lq & 19) | ((lq & 4) << 1) | ((lq & 8) >> 1);  // swap bits 2,3

  // staging mapping: 512 threads cover one [64][64] bf16 tile, 16B each
  const int srow = tid >> 3;          // 0..63
  const int scol = (tid & 7) * 8;     // 0..56 step 8

  // Q B-fragments: col=lq, k=d = ds*16 + hi*8 + j
  short8 qf[4];
#pragma unroll
  for (int ds = 0; ds < 4; ++ds)
    qf[ds] = ld8(Qp + (size_t)(q0 + lq) * 64 + ds * 16 + hi * 8);

  f32x16 acc0 = {}, acc1 = {};
  float mrun = -1e30f, lrun = 0.f;    // lrun = OWN-HALF partial sum

  // ---- prologue: stage tile 0, prefetch tile 1 into regs ----
  short8 kst = ld8(Kp + (size_t)srow * 64 + scol);
  short8 vst = ld8(Vp + (size_t)srow * 2048 + scol);
  *reinterpret_cast<short8*>(&Kl[0][srow][scol]) = kst;
  *reinterpret_cast<short8*>(&Vl[0][srow][scol]) = vst;
  kst = ld8(Kp + (size_t)(64 + srow) * 64 + scol);
  vst = ld8(Vp + (size_t)srow * 2048 + 64 + scol);
  __syncthreads();

  for (int t = 0; t < 32; ++t) {
    const int cur = t & 1;

    // ---- K frags from LDS (rows blq / 32+blq pre-permuted) ----
    short8 kf0 = ld8(&Kl[cur][blq][ 0 + hi * 8]);
    short8 kf1 = ld8(&Kl[cur][blq][16 + hi * 8]);
    short8 kf2 = ld8(&Kl[cur][blq][32 + hi * 8]);
    short8 kf3 = ld8(&Kl[cur][blq][48 + hi * 8]);
    short8 kf4 = ld8(&Kl[cur][32 + blq][ 0 + hi * 8]);
    short8 kf5 = ld8(&Kl[cur][32 + blq][16 + hi * 8]);
    short8 kf6 = ld8(&Kl[cur][32 + blq][32 + hi * 8]);
    short8 kf7 = ld8(&Kl[cur][32 + blq][48 + hi * 8]);

    // ---- QK^T: two independent 32-kv chains ----
    f32x16 sp0 = {}, sp1 = {};
    __builtin_amdgcn_s_setprio(1);
    sp0 = __builtin_amdgcn_mfma_f32_32x32x16_bf16(kf0, qf[0], sp0, 0, 0, 0);
    sp1 = __builtin_amdgcn_mfma_f32_32x32x16_bf16(kf4, qf[0], sp1, 0, 0, 0);
    sp0 = __builtin_amdgcn_mfma_f32_32x32x16_bf16(kf1, qf[1], sp0, 0, 0, 0);
    sp1 = __builtin_amdgcn_mfma_f32_32x32x16_bf16(kf5, qf[1], sp1, 0, 0, 0);
    sp0 = __builtin_amdgcn_mfma_f32_32x32x16_bf16(kf2, qf[2], sp0, 0, 0, 0);
    sp1 = __builtin_amdgcn_mfma_f32_32x32x16_bf16(kf6, qf[2], sp1, 0, 0, 0);
    sp0 = __builtin_amdgcn_mfma_f32_32x32x16_bf16(kf3, qf[3], sp0, 0, 0, 0);
    sp1 = __builtin_amdgcn_mfma_f32_32x32x16_bf16(kf7, qf[3], sp1, 0, 0, 0);
    __builtin_amdgcn_s_setprio(0);

    // ---- V frags from LDS (independent of softmax; latency hidden under it) ----
    short8 vf0 = ld8(&Vl[cur][lq][ 0 + hi * 8]);
    short8 vf1 = ld8(&Vl[cur][32 + lq][ 0 + hi * 8]);
    short8 vf2 = ld8(&Vl[cur][lq][16 + hi * 8]);
    short8 vf3 = ld8(&Vl[cur][32 + lq][16 + hi * 8]);
    short8 vf4 = ld8(&Vl[cur][lq][32 + hi * 8]);
    short8 vf5 = ld8(&Vl[cur][32 + lq][32 + hi * 8]);
    short8 vf6 = ld8(&Vl[cur][lq][48 + hi * 8]);
    short8 vf7 = ld8(&Vl[cur][32 + lq][48 + hi * 8]);

    // ---- online softmax (log2 domain) over 32 lane-local scores ----
    float ta = vmax3(sp0[0], sp0[1], sp0[2]);
    float tb = vmax3(sp0[3], sp0[4], sp0[5]);
    float tc = vmax3(sp0[6], sp0[7], sp0[8]);
    float td = vmax3(sp0[9], sp0[10], sp0[11]);
    ta = vmax3(ta, sp0[12], sp0[13]);
    tb = vmax3(tb, sp0[14], sp0[15]);
    tc = vmax3(tc, sp1[0], sp1[1]);
    td = vmax3(td, sp1[2], sp1[3]);
    ta = vmax3(ta, sp1[4], sp1[5]);
    tb = vmax3(tb, sp1[6], sp1[7]);
    tc = vmax3(tc, sp1[8], sp1[9]);
    td = vmax3(td, sp1[10], sp1[11]);
    ta = vmax3(ta, sp1[12], sp1[13]);
    tb = vmax3(tb, sp1[14], sp1[15]);
    float tm = fmaxf(vmax3(ta, tb, tc), td);
    float tmx = fmaxf(tm, __shfl_xor(tm, 32));
    if (!__all(tmx <= mrun + 11.0f)) {   // defer-max: P bounded by 2^11
      float mn = fmaxf(mrun, tmx);
      float alpha = vexp2(mrun - mn);    // uniform across both halves
      mrun = mn;
      lrun *= alpha;
#pragma unroll
      for (int i = 0; i < 16; ++i) { acc0[i] *= alpha; acc1[i] *= alpha; }
    }
    float p0[16], p1[16];
    float s0 = 0.f, s1 = 0.f, s2 = 0.f, s3 = 0.f;
    float s4 = 0.f, s5 = 0.f, s6 = 0.f, s7 = 0.f;
#pragma unroll
    for (int i = 0; i < 4; ++i) {
      p0[4 * i]     = vexp2(sp0[4 * i]     - mrun); s0 += p0[4 * i];
      p0[4 * i + 1] = vexp2(sp0[4 * i + 1] - mrun); s1 += p0[4 * i + 1];
      p0[4 * i + 2] = vexp2(sp0[4 * i + 2] - mrun); s2 += p0[4 * i + 2];
      p0[4 * i + 3] = vexp2(sp0[4 * i + 3] - mrun); s3 += p0[4 * i + 3];
      p1[4 * i]     = vexp2(sp1[4 * i]     - mrun); s4 += p1[4 * i];
      p1[4 * i + 1] = vexp2(sp1[4 * i + 1] - mrun); s5 += p1[4 * i + 1];
      p1[4 * i + 2] = vexp2(sp1[4 * i + 2] - mrun); s6 += p1[4 * i + 2];
      p1[4 * i + 3] = vexp2(sp1[4 * i + 3] - mrun); s7 += p1[4 * i + 3];
    }
    lrun += ((s0 + s1) + (s2 + s3)) + ((s4 + s5) + (s6 + s7));

    // ---- P -> bf16 B-fragments, NO cross-lane ops (K rows pre-permuted) ----
    union { int w[4]; short8 v; } pf0, pf1, pf2, pf3;
#pragma unroll
    for (int w = 0; w < 4; ++w) {
      pf0.w[w] = cvtpk(p0[2 * w],     p0[2 * w + 1]);
      pf1.w[w] = cvtpk(p0[8 + 2 * w], p0[9 + 2 * w]);
      pf2.w[w] = cvtpk(p1[2 * w],     p1[2 * w + 1]);
      pf3.w[w] = cvtpk(p1[8 + 2 * w], p1[9 + 2 * w]);
    }

    // ---- PV: O^T[d][q] += V^T x P, two independent d-chains ----
    __builtin_amdgcn_s_setprio(1);
    acc0 = __builtin_amdgcn_mfma_f32_32x32x16_bf16(vf0, pf0.v, acc0, 0, 0, 0);
    acc1 = __builtin_amdgcn_mfma_f32_32x32x16_bf16(vf1, pf0.v, acc1, 0, 0, 0);
    acc0 = __builtin_amdgcn_mfma_f32_32x32x16_bf16(vf2, pf1.v, acc0, 0, 0, 0);
    acc1 = __builtin_amdgcn_mfma_f32_32x32x16_bf16(vf3, pf1.v, acc1, 0, 0, 0);
    acc0 = __builtin_amdgcn_mfma_f32_32x32x16_bf16(vf4, pf2.v, acc0, 0, 0, 0);
    acc1 = __builtin_amdgcn_mfma_f32_32x32x16_bf16(vf5, pf2.v, acc1, 0, 0, 0);
    acc0 = __builtin_amdgcn_mfma_f32_32x32x16_bf16(vf6, pf3.v, acc0, 0, 0, 0);
    acc1 = __builtin_amdgcn_mfma_f32_32x32x16_bf16(vf7, pf3.v, acc1, 0, 0, 0);
    __builtin_amdgcn_s_setprio(0);

    // ---- T14 write-late stage + single barrier; issue-early next loads ----
    if (t < 31) {
      *reinterpret_cast<short8*>(&Kl[cur ^ 1][srow][scol]) = kst;
      *reinterpret_cast<short8*>(&Vl[cur ^ 1][srow][scol]) = vst;
      __syncthreads();
      if (t < 30) {
        kst = ld8(Kp + (size_t)((t + 2) * 64 + srow) * 64 + scol);
        vst = ld8(Vp + (size_t)srow * 2048 + (t + 2) * 64 + scol);
      }
    }
  }

  // ---- epilogue: deferred cross-half l-sum, direct write (no merge) ----
  float lfull = lrun + __shfl_xor(lrun, 32);
  float rl = 1.0f / lfull;
  const int b = bh >> 3, h = bh & 7;
  unsigned short* base = attn + ((size_t)(b * 2048 + q0 + lq)) * 512 + h * 64;
#pragma unroll
  for (int g = 0; g < 4; ++g) {
    u16x4 oa, ob;
#pragma unroll
    for (int j = 0; j < 4; ++j) {
      oa[j] = f2bf(acc0[4 * g + j] * rl);
      ob[j] = f2bf(acc1[4 * g + j] * rl);
    }
    *reinterpret_cast<u16x4*>(base + 8 * g + 4 * hi) = oa;
    *reinterpret_cast<u16x4*>(base + 32 + 8 * g + 4 * hi) = ob;
  }
}

// ---------------------------------------------------------------------------
// Output projection: out(fp32) = attn(bf16)[8192,512] @ W_o^T + b_o
// ---------------------------------------------------------------------------
__global__ __launch_bounds__(256) void out_gemm(
    const unsigned short* __restrict__ A, const float* __restrict__ W,
    const float* __restrict__ bias, float* __restrict__ out)
{
  __shared__ unsigned short Al[128][40];
  __shared__ unsigned short Bl[128][40];
  const int tid = threadIdx.x;
  const int lane = tid & 63;
  const int g = lane >> 4, c = lane & 15;
  const int wave = tid >> 6;
  const int m0 = blockIdx.x * 128, n0 = blockIdx.y * 128;
  const int wm = (wave & 1) * 64, wn = (wave >> 1) * 64;
  f32x4 acc[4][4] = {};

  const int arow = tid >> 2;
  const int acol = (tid & 3) * 8;
  const int srow = tid >> 3;
  const int scol = (tid & 7) * 4;

  for (int k0 = 0; k0 < 512; k0 += 32) {
    __syncthreads();
#pragma unroll
    for (int p = 0; p < 2; ++p) {
      int row = p * 64 + arow;
      short8 av = ld8(&A[(size_t)(m0 + row) * 512 + k0 + acol]);
      *reinterpret_cast<short8*>(&Al[row][acol]) = av;
    }
#pragma unroll
    for (int p = 0; p < 4; ++p) {
      int row = p * 32 + srow;
      f32x4 wv = *reinterpret_cast<const f32x4*>(&W[(size_t)(n0 + row) * 512 + k0 + scol]);
      u16x4 wb = { f2bf(wv[0]), f2bf(wv[1]), f2bf(wv[2]), f2bf(wv[3]) };
      *reinterpret_cast<u16x4*>(&Bl[row][scol]) = wb;
    }
    __syncthreads();
    short8 af[4], bfr[4];
#pragma unroll
    for (int i = 0; i < 4; ++i) {
      af[i]  = ld8(&Al[wm + i * 16 + c][g * 8]);
      bfr[i] = ld8(&Bl[wn + i * 16 + c][g * 8]);
    }
#pragma unroll
    for (int i = 0; i < 4; ++i)
#pragma unroll
      for (int j = 0; j < 4; ++j)
        acc[i][j] = __builtin_amdgcn_mfma_f32_16x16x32_bf16(af[i], bfr[j], acc[i][j], 0, 0, 0);
  }

#pragma unroll
  for (int j = 0; j < 4; ++j) {
    int col = n0 + wn + j * 16 + c;
    float bcol = bias[col];
#pragma unroll
    for (int i = 0; i < 4; ++i)
#pragma unroll
      for (int r = 0; r < 4; ++r) {
        int row = m0 + wm + i * 16 + g * 4 + r;
        out[(size_t)row * 512 + col] = acc[i][j][r] + bcol;
      }
  }
}

extern "C" void kernel_launch(void* const* d_in, const int* in_sizes, int n_in,
                              void* d_out, int out_size, void* d_ws, size_t ws_size,
                              hipStream_t stream)
{
  const float* q  = (const float*)d_in[0];
  const float* k  = (const float*)d_in[1];
  const float* v  = (const float*)d_in[2];
  const float* Wq = (const float*)d_in[3];
  const float* bq = (const float*)d_in[4];
  const float* Wk = (const float*)d_in[5];
  const float* bk = (const float*)d_in[6];
  const float* Wv = (const float*)d_in[7];
  const float* bv = (const float*)d_in[8];
  const float* Wo = (const float*)d_in[9];
  const float* bo = (const float*)d_in[10];
  float* out = (float*)d_out;

  unsigned short* ws = (unsigned short*)d_ws;
  unsigned short* Qh = ws;                              // [32][2048][64] (pre-scaled log2e/8)
  unsigned short* Kh = ws + (size_t)4 * 1024 * 1024;    // [32][2048][64]
  unsigned short* Vt = ws + (size_t)8 * 1024 * 1024;    // [32][64][2048]
  unsigned short* at = ws + (size_t)12 * 1024 * 1024;   // [4][2048][512]

  dim3 blk(256);
  proj3<<<dim3(64, 4, 3), blk, 0, stream>>>(q, k, v, Wq, Wk, Wv, bq, bk, bv, Qh, Kh, Vt);
  flash_attn<<<dim3(256), dim3(512), 0, stream>>>(Qh, Kh, Vt, at);
  out_gemm<<<dim3(64, 4), blk, 0, stream>>>(at, Wo, bo, out);
}

// Round 12
// 196.892 us; speedup vs baseline: 1.0278x; 1.0079x over previous
//
#include <hip/hip_runtime.h>
#include <hip/hip_bf16.h>

// MultiHeadAttention: B=4, S=2048, D_MODEL=512, N_HEAD=8, D_K=64
// Pipeline: proj3 (Q*log2e/8, K, V->transposed fused), flash_attn (T15 software-pipelined,
// 4-way split KV, XCD-pinned), out_gemm

typedef __attribute__((ext_vector_type(8))) short short8;
typedef __attribute__((ext_vector_type(4))) float f32x4;
typedef __attribute__((ext_vector_type(16))) float f32x16;
typedef __attribute__((ext_vector_type(4))) unsigned short u16x4;

union pack_t { int w[4]; short8 v; };

static __device__ __forceinline__ unsigned short f2bf(float x) {
  union { float f; unsigned u; } v; v.f = x;
  unsigned r = v.u + 0x7fffu + ((v.u >> 16) & 1u);  // round-to-nearest-even
  return (unsigned short)(r >> 16);
}

static __device__ __forceinline__ short8 ld8(const unsigned short* p) {
  return *reinterpret_cast<const short8*>(p);
}

static __device__ __forceinline__ float vmax3(float a, float b, float c) {
  float r; asm("v_max3_f32 %0, %1, %2, %3" : "=v"(r) : "v"(a), "v"(b), "v"(c)); return r;
}

static __device__ __forceinline__ float vexp2(float x) {
  float r; asm("v_exp_f32 %0, %1" : "=v"(r) : "v"(x)); return r;
}

static __device__ __forceinline__ int cvtpk(float a, float b) {
  int r; asm("v_cvt_pk_bf16_f32 %0, %1, %2" : "=v"(r) : "v"(a), "v"(b)); return r;
}

// ---------------------------------------------------------------------------
// Fused projection GEMMs: z = blockIdx.z selects {Q, K, V}. (unchanged, verified)
// ---------------------------------------------------------------------------
__global__ __launch_bounds__(256) void proj3(
    const float* __restrict__ Xq, const float* __restrict__ Xk, const float* __restrict__ Xv,
    const float* __restrict__ Wq, const float* __restrict__ Wk, const float* __restrict__ Wv,
    const float* __restrict__ bq, const float* __restrict__ bk, const float* __restrict__ bv,
    unsigned short* __restrict__ Qh, unsigned short* __restrict__ Kh,
    unsigned short* __restrict__ Vt)
{
  const int z = blockIdx.z;
  const float* X = z == 0 ? Xq : z == 1 ? Xk : Xv;
  const float* W = z == 0 ? Wq : z == 1 ? Wk : Wv;
  const float* bias = z == 0 ? bq : z == 1 ? bk : bv;
  unsigned short* dst = z == 0 ? Qh : z == 1 ? Kh : Vt;
  const int vmode = (z == 2);
  const float oscale = z == 0 ? 0.1803368801f : 1.0f;  // (1/8)*log2(e)

  __shared__ unsigned short Al[128][40];
  __shared__ unsigned short Bl[128][40];
  const int tid = threadIdx.x;
  const int lane = tid & 63;
  const int g = lane >> 4, c = lane & 15;
  const int wave = tid >> 6;
  const int m0 = blockIdx.x * 128, n0 = blockIdx.y * 128;
  const int wm = (wave & 1) * 64, wn = (wave >> 1) * 64;
  f32x4 acc[4][4] = {};

  const int srow = tid >> 3;
  const int scol = (tid & 7) * 4;

  for (int k0 = 0; k0 < 512; k0 += 32) {
    __syncthreads();
#pragma unroll
    for (int p = 0; p < 4; ++p) {
      int row = p * 32 + srow;
      f32x4 xv = *reinterpret_cast<const f32x4*>(&X[(size_t)(m0 + row) * 512 + k0 + scol]);
      u16x4 xb = { f2bf(xv[0]), f2bf(xv[1]), f2bf(xv[2]), f2bf(xv[3]) };
      *reinterpret_cast<u16x4*>(&Al[row][scol]) = xb;
      f32x4 wv = *reinterpret_cast<const f32x4*>(&W[(size_t)(n0 + row) * 512 + k0 + scol]);
      u16x4 wb = { f2bf(wv[0]), f2bf(wv[1]), f2bf(wv[2]), f2bf(wv[3]) };
      *reinterpret_cast<u16x4*>(&Bl[row][scol]) = wb;
    }
    __syncthreads();
    short8 af[4], bfr[4];
#pragma unroll
    for (int i = 0; i < 4; ++i) {
      af[i]  = ld8(&Al[wm + i * 16 + c][g * 8]);
      bfr[i] = ld8(&Bl[wn + i * 16 + c][g * 8]);
    }
#pragma unroll
    for (int i = 0; i < 4; ++i)
#pragma unroll
      for (int j = 0; j < 4; ++j)
        acc[i][j] = __builtin_amdgcn_mfma_f32_16x16x32_bf16(af[i], bfr[j], acc[i][j], 0, 0, 0);
  }

#pragma unroll
  for (int j = 0; j < 4; ++j) {
    int col = n0 + wn + j * 16 + c;
    float bcol = bias[col];
    int h = col >> 6, d = col & 63;
#pragma unroll
    for (int i = 0; i < 4; ++i) {
#pragma unroll
      for (int r = 0; r < 4; ++r) {
        int row = m0 + wm + i * 16 + g * 4 + r;
        int b = row >> 11, s = row & 2047;
        float val = (acc[i][j][r] + bcol) * oscale;
        size_t idx = vmode ? ((size_t)((b * 8 + h) * 64 + d) * 2048 + s)
                           : ((size_t)((b * 8 + h) * 2048 + s) * 64 + d);
        dst[idx] = f2bf(val);
      }
    }
  }
}

// ---------------------------------------------------------------------------
// flash_attn helpers
// ---------------------------------------------------------------------------
static __device__ __forceinline__ f32x16 qk_step(
    const short8* qf, short8 k0, short8 k1, short8 k2, short8 k3)
{
  f32x16 sp = {};
  sp = __builtin_amdgcn_mfma_f32_32x32x16_bf16(k0, qf[0], sp, 0, 0, 0);
  sp = __builtin_amdgcn_mfma_f32_32x32x16_bf16(k1, qf[1], sp, 0, 0, 0);
  sp = __builtin_amdgcn_mfma_f32_32x32x16_bf16(k2, qf[2], sp, 0, 0, 0);
  sp = __builtin_amdgcn_mfma_f32_32x32x16_bf16(k3, qf[3], sp, 0, 0, 0);
  return sp;
}

static __device__ __forceinline__ void pv_step(
    short8 v0, short8 v1, short8 v2, short8 v3,
    const pack_t& pf0, const pack_t& pf1, f32x16& acc0, f32x16& acc1)
{
  acc0 = __builtin_amdgcn_mfma_f32_32x32x16_bf16(v0, pf0.v, acc0, 0, 0, 0);
  acc1 = __builtin_amdgcn_mfma_f32_32x32x16_bf16(v1, pf0.v, acc1, 0, 0, 0);
  acc0 = __builtin_amdgcn_mfma_f32_32x32x16_bf16(v2, pf1.v, acc0, 0, 0, 0);
  acc1 = __builtin_amdgcn_mfma_f32_32x32x16_bf16(v3, pf1.v, acc1, 0, 0, 0);
}

// online softmax over 16 lane-local scores (log2 domain) -> two PV B-fragments
static __device__ __forceinline__ void softmax_step(
    const f32x16& sp, float& mrun, float& lrun,
    f32x16& acc0, f32x16& acc1, pack_t& pf0, pack_t& pf1)
{
  float ta = vmax3(sp[0], sp[1], sp[2]);
  float tb = vmax3(sp[3], sp[4], sp[5]);
  float tc = vmax3(sp[6], sp[7], sp[8]);
  float td = vmax3(sp[9], sp[10], sp[11]);
  ta = vmax3(ta, sp[12], sp[13]);
  tb = vmax3(tb, sp[14], sp[15]);
  float tm = fmaxf(vmax3(ta, tb, tc), td);
  float tmx = fmaxf(tm, __shfl_xor(tm, 32));
  if (!__all(tmx <= mrun + 11.0f)) {   // defer-max: P bounded by 2^11
    float mn = fmaxf(mrun, tmx);
    float alpha = vexp2(mrun - mn);
    mrun = mn; lrun *= alpha;
#pragma unroll
    for (int i = 0; i < 16; ++i) { acc0[i] *= alpha; acc1[i] *= alpha; }
  }
  float p[16];
  float s0 = 0.f, s1 = 0.f, s2 = 0.f, s3 = 0.f;
#pragma unroll
  for (int i = 0; i < 4; ++i) {
    p[4 * i]     = vexp2(sp[4 * i]     - mrun); s0 += p[4 * i];
    p[4 * i + 1] = vexp2(sp[4 * i + 1] - mrun); s1 += p[4 * i + 1];
    p[4 * i + 2] = vexp2(sp[4 * i + 2] - mrun); s2 += p[4 * i + 2];
    p[4 * i + 3] = vexp2(sp[4 * i + 3] - mrun); s3 += p[4 * i + 3];
  }
  lrun += (s0 + s1) + (s2 + s3);   // own-half partial; cross-half deferred to merge
#pragma unroll
  for (int w = 0; w < 4; ++w) {
    pf0.w[w] = cvtpk(p[2 * w],     p[2 * w + 1]);
    pf1.w[w] = cvtpk(p[8 + 2 * w], p[9 + 2 * w]);
  }
}

// ---------------------------------------------------------------------------
// Flash attention, T15 software pipeline: per 32-kv step s, issue QK(s+1) and
// PV(s) together (independent: sp vs acc, kf vs vf/pf) so the MFMA pipe has
// work while softmax(s+1)'s VALU/trans dep-chain runs — the r4-r11 plateau was
// 74% dependency stall with every pipe <20% busy.
// Base: r7/r8 verified math. 4 waves/block = 4 kv-quarters (split-KV, LDS
// merge), XCD-pinned heads (bh=4*(n&7)+((n>>3)&3)), K rows pre-permuted via
// blq (swap bits 2<->3) so cvt_pk output IS the PV B-fragment. Even/odd
// register sets (static names, no runtime indexing).
// ---------------------------------------------------------------------------
__global__ __launch_bounds__(256) void flash_attn(
    const unsigned short* __restrict__ Qh, const unsigned short* __restrict__ Kh,
    const unsigned short* __restrict__ Vt, unsigned short* __restrict__ attn)
{
  __shared__ float Mred[4][32];
  __shared__ float Lred[4][32];
  __shared__ float AccO[2][64][32];   // [stage][d][q]
  const int lane = threadIdx.x & 63;
  const int kh = threadIdx.x >> 6;    // kv quarter
  const int lq = lane & 31;           // q column / frag row
  const int hi = lane >> 5;           // lane half
  const int n = blockIdx.y * 64 + blockIdx.x;
  const int bh = 4 * (n & 7) + ((n >> 3) & 3);   // XCD-pinned head
  const int q0 = (n >> 5) * 32;
  const unsigned short* Qp = Qh + (size_t)bh * 2048 * 64;
  const unsigned short* Kp = Kh + (size_t)bh * 2048 * 64;
  const unsigned short* Vp = Vt + (size_t)bh * 64 * 2048;
  const int blq = (lq & 19) | ((lq & 4) << 1) | ((lq & 8) >> 1);  // swap bits 2,3

  // Q B-fragments: col=lq, k=d = ds*16 + hi*8 + j
  short8 qf[4];
#pragma unroll
  for (int ds = 0; ds < 4; ++ds)
    qf[ds] = ld8(Qp + (size_t)(q0 + lq) * 64 + ds * 16 + hi * 8);

  // bases for this wave's kv quarter; step s covers kv = kh*512 + s*32
  const unsigned short* Kb  = Kp + (size_t)(kh * 512 + blq) * 64 + hi * 8;
  const unsigned short* Vb0 = Vp + (size_t)lq * 2048        + kh * 512 + hi * 8;
  const unsigned short* Vb1 = Vp + (size_t)(32 + lq) * 2048 + kh * 512 + hi * 8;

#define LOADK(s, a, b, c, d) do {                                           \
    const unsigned short* kp_ = Kb + (size_t)(s) * 2048;                    \
    a = ld8(kp_); b = ld8(kp_ + 16); c = ld8(kp_ + 32); d = ld8(kp_ + 48);  \
  } while (0)
#define LOADV(s, a, b, c, d) do {                                           \
    a = ld8(Vb0 + (s) * 32);      b = ld8(Vb1 + (s) * 32);                  \
    c = ld8(Vb0 + (s) * 32 + 16); d = ld8(Vb1 + (s) * 32 + 16);             \
  } while (0)

  f32x16 acc0 = {}, acc1 = {};
  float mrun = -1e30f, lrun = 0.f;    // lrun = own-half partial sum

  short8 kE0, kE1, kE2, kE3, kO0, kO1, kO2, kO3;
  short8 vE0, vE1, vE2, vE3, vO0, vO1, vO2, vO3;
  pack_t pE0, pE1, pO0, pO1;
  f32x16 spE, spO;

  // ---- prologue: step 0 QK+softmax; loads for steps 0,1 ----
  LOADK(0, kE0, kE1, kE2, kE3);
  LOADV(0, vE0, vE1, vE2, vE3);
  LOADK(1, kO0, kO1, kO2, kO3);
  spE = qk_step(qf, kE0, kE1, kE2, kE3);
  LOADV(1, vO0, vO1, vO2, vO3);
  softmax_step(spE, mrun, lrun, acc0, acc1, pE0, pE1);

  // steady state invariant at loop top (s even):
  //   pE/vE = step s; kO = K(s+1); vO = V(s+1)
  for (int s = 0; s < 14; s += 2) {
    // --- phase A: QK(s+1) || PV(s) (independent MFMA work) ---
    __builtin_amdgcn_s_setprio(1);
    spO = qk_step(qf, kO0, kO1, kO2, kO3);
    pv_step(vE0, vE1, vE2, vE3, pE0, pE1, acc0, acc1);
    __builtin_amdgcn_s_setprio(0);
    LOADK(s + 2, kE0, kE1, kE2, kE3);
    LOADV(s + 2, vE0, vE1, vE2, vE3);
    softmax_step(spO, mrun, lrun, acc0, acc1, pO0, pO1);
    // --- phase B: QK(s+2) || PV(s+1) ---
    __builtin_amdgcn_s_setprio(1);
    spE = qk_step(qf, kE0, kE1, kE2, kE3);
    pv_step(vO0, vO1, vO2, vO3, pO0, pO1, acc0, acc1);
    __builtin_amdgcn_s_setprio(0);
    LOADK(s + 3, kO0, kO1, kO2, kO3);
    LOADV(s + 3, vO0, vO1, vO2, vO3);
    softmax_step(spE, mrun, lrun, acc0, acc1, pE0, pE1);
  }
  // tail: pE = pf(14), vE = V(14), kO = K(15), vO = V(15)
  spO = qk_step(qf, kO0, kO1, kO2, kO3);               // QK(15)
  pv_step(vE0, vE1, vE2, vE3, pE0, pE1, acc0, acc1);   // PV(14)
  softmax_step(spO, mrun, lrun, acc0, acc1, pO0, pO1); // softmax(15)
  pv_step(vO0, vO1, vO2, vO3, pO0, pO1, acc0, acc1);   // PV(15)
#undef LOADK
#undef LOADV

  // ---- 4-way merge via staged LDS accumulate (r8-verified) ----
  float lfull = lrun + __shfl_xor(lrun, 32);   // deferred cross-half l-sum
  if (lane < 32) { Mred[kh][lq] = mrun; Lred[kh][lq] = lfull; }
  __syncthreads();
  float m = fmaxf(fmaxf(Mred[0][lq], Mred[1][lq]), fmaxf(Mred[2][lq], Mred[3][lq]));
  float ltot = Lred[0][lq] * vexp2(Mred[0][lq] - m)
             + Lred[1][lq] * vexp2(Mred[1][lq] - m)
             + Lred[2][lq] * vexp2(Mred[2][lq] - m)
             + Lred[3][lq] * vexp2(Mred[3][lq] - m);
  float sc = vexp2(mrun - m);
#pragma unroll
  for (int i = 0; i < 16; ++i) { acc0[i] *= sc; acc1[i] *= sc; }
  if (kh >= 2) {
#pragma unroll
    for (int i = 0; i < 16; ++i) {
      int d = (i & 3) + 8 * (i >> 2) + 4 * hi;
      AccO[kh - 2][d][lq]      = acc0[i];
      AccO[kh - 2][32 + d][lq] = acc1[i];
    }
  }
  __syncthreads();
  if (kh < 2) {
#pragma unroll
    for (int i = 0; i < 16; ++i) {
      int d = (i & 3) + 8 * (i >> 2) + 4 * hi;
      AccO[kh][d][lq]      += acc0[i];
      AccO[kh][32 + d][lq] += acc1[i];
    }
  }
  __syncthreads();
  if (kh < 2) {
    float rl = 1.0f / ltot;
    const int b = bh >> 3, h = bh & 7;
    unsigned short* base = attn + ((size_t)(b * 2048 + q0 + lq)) * 512 + h * 64
                         + kh * 32 + hi * 16;
    union { unsigned short u[16]; short8 v[2]; } ov;
#pragma unroll
    for (int dd = 0; dd < 16; ++dd) {
      int d = kh * 32 + hi * 16 + dd;
      ov.u[dd] = f2bf((AccO[0][d][lq] + AccO[1][d][lq]) * rl);
    }
    *reinterpret_cast<short8*>(base) = ov.v[0];
    *reinterpret_cast<short8*>(base + 8) = ov.v[1];
  }
}

// ---------------------------------------------------------------------------
// Output projection: out(fp32) = attn(bf16)[8192,512] @ W_o^T + b_o (unchanged)
// ---------------------------------------------------------------------------
__global__ __launch_bounds__(256) void out_gemm(
    const unsigned short* __restrict__ A, const float* __restrict__ W,
    const float* __restrict__ bias, float* __restrict__ out)
{
  __shared__ unsigned short Al[128][40];
  __shared__ unsigned short Bl[128][40];
  const int tid = threadIdx.x;
  const int lane = tid & 63;
  const int g = lane >> 4, c = lane & 15;
  const int wave = tid >> 6;
  const int m0 = blockIdx.x * 128, n0 = blockIdx.y * 128;
  const int wm = (wave & 1) * 64, wn = (wave >> 1) * 64;
  f32x4 acc[4][4] = {};

  const int arow = tid >> 2;
  const int acol = (tid & 3) * 8;
  const int srow = tid >> 3;
  const int scol = (tid & 7) * 4;

  for (int k0 = 0; k0 < 512; k0 += 32) {
    __syncthreads();
#pragma unroll
    for (int p = 0; p < 2; ++p) {
      int row = p * 64 + arow;
      short8 av = ld8(&A[(size_t)(m0 + row) * 512 + k0 + acol]);
      *reinterpret_cast<short8*>(&Al[row][acol]) = av;
    }
#pragma unroll
    for (int p = 0; p < 4; ++p) {
      int row = p * 32 + srow;
      f32x4 wv = *reinterpret_cast<const f32x4*>(&W[(size_t)(n0 + row) * 512 + k0 + scol]);
      u16x4 wb = { f2bf(wv[0]), f2bf(wv[1]), f2bf(wv[2]), f2bf(wv[3]) };
      *reinterpret_cast<u16x4*>(&Bl[row][scol]) = wb;
    }
    __syncthreads();
    short8 af[4], bfr[4];
#pragma unroll
    for (int i = 0; i < 4; ++i) {
      af[i]  = ld8(&Al[wm + i * 16 + c][g * 8]);
      bfr[i] = ld8(&Bl[wn + i * 16 + c][g * 8]);
    }
#pragma unroll
    for (int i = 0; i < 4; ++i)
#pragma unroll
      for (int j = 0; j < 4; ++j)
        acc[i][j] = __builtin_amdgcn_mfma_f32_16x16x32_bf16(af[i], bfr[j], acc[i][j], 0, 0, 0);
  }

#pragma unroll
  for (int j = 0; j < 4; ++j) {
    int col = n0 + wn + j * 16 + c;
    float bcol = bias[col];
#pragma unroll
    for (int i = 0; i < 4; ++i)
#pragma unroll
      for (int r = 0; r < 4; ++r) {
        int row = m0 + wm + i * 16 + g * 4 + r;
        out[(size_t)row * 512 + col] = acc[i][j][r] + bcol;
      }
  }
}

extern "C" void kernel_launch(void* const* d_in, const int* in_sizes, int n_in,
                              void* d_out, int out_size, void* d_ws, size_t ws_size,
                              hipStream_t stream)
{
  const float* q  = (const float*)d_in[0];
  const float* k  = (const float*)d_in[1];
  const float* v  = (const float*)d_in[2];
  const float* Wq = (const float*)d_in[3];
  const float* bq = (const float*)d_in[4];
  const float* Wk = (const float*)d_in[5];
  const float* bk = (const float*)d_in[6];
  const float* Wv = (const float*)d_in[7];
  const float* bv = (const float*)d_in[8];
  const float* Wo = (const float*)d_in[9];
  const float* bo = (const float*)d_in[10];
  float* out = (float*)d_out;

  unsigned short* ws = (unsigned short*)d_ws;
  unsigned short* Qh = ws;                              // [32][2048][64] (pre-scaled log2e/8)
  unsigned short* Kh = ws + (size_t)4 * 1024 * 1024;    // [32][2048][64]
  unsigned short* Vt = ws + (size_t)8 * 1024 * 1024;    // [32][64][2048]
  unsigned short* at = ws + (size_t)12 * 1024 * 1024;   // [4][2048][512]

  dim3 blk(256);
  proj3<<<dim3(64, 4, 3), blk, 0, stream>>>(q, k, v, Wq, Wk, Wv, bq, bk, bv, Qh, Kh, Vt);
  flash_attn<<<dim3(64, 32), blk, 0, stream>>>(Qh, Kh, Vt, at);
  out_gemm<<<dim3(64, 4), blk, 0, stream>>>(at, Wo, bo, out);
}

// Round 13
// 141.752 us; speedup vs baseline: 1.4276x; 1.3890x over previous
//
#include <hip/hip_runtime.h>
#include <hip/hip_bf16.h>

// MultiHeadAttention: B=4, S=2048, D_MODEL=512, N_HEAD=8, D_K=64
// Pipeline: proj3, flash_attn (2 q-tiles/wave: amortize dep-chain), out_gemm

typedef __attribute__((ext_vector_type(8))) short short8;
typedef __attribute__((ext_vector_type(4))) float f32x4;
typedef __attribute__((ext_vector_type(16))) float f32x16;
typedef __attribute__((ext_vector_type(4))) unsigned short u16x4;

union pack_t { int w[4]; short8 v; };

static __device__ __forceinline__ unsigned short f2bf(float x) {
  union { float f; unsigned u; } v; v.f = x;
  unsigned r = v.u + 0x7fffu + ((v.u >> 16) & 1u);
  return (unsigned short)(r >> 16);
}

static __device__ __forceinline__ short8 ld8(const unsigned short* p) {
  return *reinterpret_cast<const short8*>(p);
}

static __device__ __forceinline__ float vmax3(float a, float b, float c) {
  float r; asm("v_max3_f32 %0, %1, %2, %3" : "=v"(r) : "v"(a), "v"(b), "v"(c)); return r;
}

static __device__ __forceinline__ float vexp2(float x) {
  float r; asm("v_exp_f32 %0, %1" : "=v"(r) : "v"(x)); return r;
}

static __device__ __forceinline__ int cvtpk(float a, float b) {
  int r; asm("v_cvt_pk_bf16_f32 %0, %1, %2" : "=v"(r) : "v"(a), "v"(b)); return r;
}

// ---------------------------------------------------------------------------
// Fused projection GEMMs (unchanged, verified)
// ---------------------------------------------------------------------------
__global__ __launch_bounds__(256) void proj3(
    const float* __restrict__ Xq, const float* __restrict__ Xk, const float* __restrict__ Xv,
    const float* __restrict__ Wq, const float* __restrict__ Wk, const float* __restrict__ Wv,
    const float* __restrict__ bq, const float* __restrict__ bk, const float* __restrict__ bv,
    unsigned short* __restrict__ Qh, unsigned short* __restrict__ Kh,
    unsigned short* __restrict__ Vt)
{
  const int z = blockIdx.z;
  const float* X = z == 0 ? Xq : z == 1 ? Xk : Xv;
  const float* W = z == 0 ? Wq : z == 1 ? Wk : Wv;
  const float* bias = z == 0 ? bq : z == 1 ? bk : bv;
  unsigned short* dst = z == 0 ? Qh : z == 1 ? Kh : Vt;
  const int vmode = (z == 2);
  const float oscale = z == 0 ? 0.1803368801f : 1.0f;  // (1/8)*log2(e)

  __shared__ unsigned short Al[128][40];
  __shared__ unsigned short Bl[128][40];
  const int tid = threadIdx.x;
  const int lane = tid & 63;
  const int g = lane >> 4, c = lane & 15;
  const int wave = tid >> 6;
  const int m0 = blockIdx.x * 128, n0 = blockIdx.y * 128;
  const int wm = (wave & 1) * 64, wn = (wave >> 1) * 64;
  f32x4 acc[4][4] = {};

  const int srow = tid >> 3;
  const int scol = (tid & 7) * 4;

  for (int k0 = 0; k0 < 512; k0 += 32) {
    __syncthreads();
#pragma unroll
    for (int p = 0; p < 4; ++p) {
      int row = p * 32 + srow;
      f32x4 xv = *reinterpret_cast<const f32x4*>(&X[(size_t)(m0 + row) * 512 + k0 + scol]);
      u16x4 xb = { f2bf(xv[0]), f2bf(xv[1]), f2bf(xv[2]), f2bf(xv[3]) };
      *reinterpret_cast<u16x4*>(&Al[row][scol]) = xb;
      f32x4 wv = *reinterpret_cast<const f32x4*>(&W[(size_t)(n0 + row) * 512 + k0 + scol]);
      u16x4 wb = { f2bf(wv[0]), f2bf(wv[1]), f2bf(wv[2]), f2bf(wv[3]) };
      *reinterpret_cast<u16x4*>(&Bl[row][scol]) = wb;
    }
    __syncthreads();
    short8 af[4], bfr[4];
#pragma unroll
    for (int i = 0; i < 4; ++i) {
      af[i]  = ld8(&Al[wm + i * 16 + c][g * 8]);
      bfr[i] = ld8(&Bl[wn + i * 16 + c][g * 8]);
    }
#pragma unroll
    for (int i = 0; i < 4; ++i)
#pragma unroll
      for (int j = 0; j < 4; ++j)
        acc[i][j] = __builtin_amdgcn_mfma_f32_16x16x32_bf16(af[i], bfr[j], acc[i][j], 0, 0, 0);
  }

#pragma unroll
  for (int j = 0; j < 4; ++j) {
    int col = n0 + wn + j * 16 + c;
    float bcol = bias[col];
    int h = col >> 6, d = col & 63;
#pragma unroll
    for (int i = 0; i < 4; ++i) {
#pragma unroll
      for (int r = 0; r < 4; ++r) {
        int row = m0 + wm + i * 16 + g * 4 + r;
        int b = row >> 11, s = row & 2047;
        float val = (acc[i][j][r] + bcol) * oscale;
        size_t idx = vmode ? ((size_t)((b * 8 + h) * 64 + d) * 2048 + s)
                           : ((size_t)((b * 8 + h) * 2048 + s) * 64 + d);
        dst[idx] = f2bf(val);
      }
    }
  }
}

// ---------------------------------------------------------------------------
// flash_attn helpers (r12-verified math)
// ---------------------------------------------------------------------------
static __device__ __forceinline__ f32x16 qk_step(
    const short8* qf, short8 k0, short8 k1, short8 k2, short8 k3)
{
  f32x16 sp = {};
  sp = __builtin_amdgcn_mfma_f32_32x32x16_bf16(k0, qf[0], sp, 0, 0, 0);
  sp = __builtin_amdgcn_mfma_f32_32x32x16_bf16(k1, qf[1], sp, 0, 0, 0);
  sp = __builtin_amdgcn_mfma_f32_32x32x16_bf16(k2, qf[2], sp, 0, 0, 0);
  sp = __builtin_amdgcn_mfma_f32_32x32x16_bf16(k3, qf[3], sp, 0, 0, 0);
  return sp;
}

static __device__ __forceinline__ void pv_step(
    short8 v0, short8 v1, short8 v2, short8 v3,
    const pack_t& pf0, const pack_t& pf1, f32x16& acc0, f32x16& acc1)
{
  acc0 = __builtin_amdgcn_mfma_f32_32x32x16_bf16(v0, pf0.v, acc0, 0, 0, 0);
  acc1 = __builtin_amdgcn_mfma_f32_32x32x16_bf16(v1, pf0.v, acc1, 0, 0, 0);
  acc0 = __builtin_amdgcn_mfma_f32_32x32x16_bf16(v2, pf1.v, acc0, 0, 0, 0);
  acc1 = __builtin_amdgcn_mfma_f32_32x32x16_bf16(v3, pf1.v, acc1, 0, 0, 0);
}

static __device__ __forceinline__ void softmax_step(
    const f32x16& sp, float& mrun, float& lrun,
    f32x16& acc0, f32x16& acc1, pack_t& pf0, pack_t& pf1)
{
  float ta = vmax3(sp[0], sp[1], sp[2]);
  float tb = vmax3(sp[3], sp[4], sp[5]);
  float tc = vmax3(sp[6], sp[7], sp[8]);
  float td = vmax3(sp[9], sp[10], sp[11]);
  ta = vmax3(ta, sp[12], sp[13]);
  tb = vmax3(tb, sp[14], sp[15]);
  float tm = fmaxf(vmax3(ta, tb, tc), td);
  float tmx = fmaxf(tm, __shfl_xor(tm, 32));
  if (!__all(tmx <= mrun + 11.0f)) {   // defer-max: P bounded by 2^11
    float mn = fmaxf(mrun, tmx);
    float alpha = vexp2(mrun - mn);
    mrun = mn; lrun *= alpha;
#pragma unroll
    for (int i = 0; i < 16; ++i) { acc0[i] *= alpha; acc1[i] *= alpha; }
  }
  float p[16];
  float s0 = 0.f, s1 = 0.f, s2 = 0.f, s3 = 0.f;
#pragma unroll
  for (int i = 0; i < 4; ++i) {
    p[4 * i]     = vexp2(sp[4 * i]     - mrun); s0 += p[4 * i];
    p[4 * i + 1] = vexp2(sp[4 * i + 1] - mrun); s1 += p[4 * i + 1];
    p[4 * i + 2] = vexp2(sp[4 * i + 2] - mrun); s2 += p[4 * i + 2];
    p[4 * i + 3] = vexp2(sp[4 * i + 3] - mrun); s3 += p[4 * i + 3];
  }
  lrun += (s0 + s1) + (s2 + s3);   // own-half partial; cross-half at merge
#pragma unroll
  for (int w = 0; w < 4; ++w) {
    pf0.w[w] = cvtpk(p[2 * w],     p[2 * w + 1]);
    pf1.w[w] = cvtpk(p[8 + 2 * w], p[9 + 2 * w]);
  }
}

// ---------------------------------------------------------------------------
// Flash attention: TWO q-tiles (64 q-rows) per wave against shared K/V frags.
// Dep-chain per 32-kv step is unchanged (two softmax chains are independent,
// ILP-2), but work per chain traversal doubles -- the lever none of r4-r12
// touched. 4 waves/block = 2 qt x 2 kv-halves; 2-way split-KV merge via LDS
// (r4-verified). XCD-pinned heads, blq-permuted K rows (shfl-free repack).
// ---------------------------------------------------------------------------
__global__ __launch_bounds__(256, 2) void flash_attn(
    const unsigned short* __restrict__ Qh, const unsigned short* __restrict__ Kh,
    const unsigned short* __restrict__ Vt, unsigned short* __restrict__ attn)
{
  __shared__ float Mred[2][2][64];   // [qt][kh][qcol 0..63]
  __shared__ float Lred[2][2][64];
  __shared__ float AccO[2][64][64];  // [qt][d][q]
  const int lane = threadIdx.x & 63;
  const int wave = threadIdx.x >> 6;
  const int qt = wave & 1;           // q sub-tile of the block
  const int kh = wave >> 1;          // kv half
  const int lq = lane & 31;
  const int hi = lane >> 5;
  const int n = blockIdx.y * 16 + blockIdx.x;     // 0..511
  const int bh = 4 * (n & 7) + ((n >> 3) & 3);    // XCD-pinned head
  const int qw = (n >> 5) * 128 + qt * 64;        // wave's 64-q base
  const unsigned short* Qp = Qh + (size_t)bh * 2048 * 64;
  const unsigned short* Kp = Kh + (size_t)bh * 2048 * 64;
  const unsigned short* Vp = Vt + (size_t)bh * 64 * 2048;
  const int blq = (lq & 19) | ((lq & 4) << 1) | ((lq & 8) >> 1);  // swap bits 2,3

  // Q B-fragments for both q-tiles
  short8 qfA[4], qfB[4];
#pragma unroll
  for (int ds = 0; ds < 4; ++ds) {
    qfA[ds] = ld8(Qp + (size_t)(qw + lq) * 64      + ds * 16 + hi * 8);
    qfB[ds] = ld8(Qp + (size_t)(qw + 32 + lq) * 64 + ds * 16 + hi * 8);
  }

  const unsigned short* Kb  = Kp + (size_t)(kh * 1024 + blq) * 64 + hi * 8;
  const unsigned short* Vb0 = Vp + (size_t)lq * 2048        + kh * 1024 + hi * 8;
  const unsigned short* Vb1 = Vp + (size_t)(32 + lq) * 2048 + kh * 1024 + hi * 8;

  short8 kf0, kf1, kf2, kf3, vf0, vf1, vf2, vf3;
#define LOADK(t) do {                                                       \
    const unsigned short* kp_ = Kb + (size_t)(t) * 2048;                    \
    kf0 = ld8(kp_); kf1 = ld8(kp_ + 16); kf2 = ld8(kp_ + 32);               \
    kf3 = ld8(kp_ + 48);                                                    \
  } while (0)
#define LOADV(t) do {                                                       \
    vf0 = ld8(Vb0 + (t) * 32);      vf1 = ld8(Vb1 + (t) * 32);              \
    vf2 = ld8(Vb0 + (t) * 32 + 16); vf3 = ld8(Vb1 + (t) * 32 + 16);         \
  } while (0)

  f32x16 accA0 = {}, accA1 = {}, accB0 = {}, accB1 = {};
  float mrunA = -1e30f, lrunA = 0.f;
  float mrunB = -1e30f, lrunB = 0.f;

  LOADK(0);
  LOADV(0);
  for (int t = 0; t < 32; ++t) {
    // ---- QK^T for both q-tiles (shared K frags) ----
    __builtin_amdgcn_s_setprio(1);
    f32x16 spA = qk_step(qfA, kf0, kf1, kf2, kf3);
    f32x16 spB = qk_step(qfB, kf0, kf1, kf2, kf3);
    __builtin_amdgcn_s_setprio(0);

    if (t < 31) LOADK(t + 1);   // kf consumed; hide under softmax+PV

    // ---- two independent softmax chains (ILP-2) ----
    pack_t pfA0, pfA1, pfB0, pfB1;
    softmax_step(spA, mrunA, lrunA, accA0, accA1, pfA0, pfA1);
    softmax_step(spB, mrunB, lrunB, accB0, accB1, pfB0, pfB1);

    // ---- PV for both q-tiles (shared V frags) ----
    __builtin_amdgcn_s_setprio(1);
    pv_step(vf0, vf1, vf2, vf3, pfA0, pfA1, accA0, accA1);
    pv_step(vf0, vf1, vf2, vf3, pfB0, pfB1, accB0, accB1);
    __builtin_amdgcn_s_setprio(0);

    if (t < 31) LOADV(t + 1);   // vf consumed; hide under next QK
  }
#undef LOADK
#undef LOADV

  // ---- 2-way split-KV merge (r4-verified structure) ----
  float lfullA = lrunA + __shfl_xor(lrunA, 32);
  float lfullB = lrunB + __shfl_xor(lrunB, 32);
  if (lane < 32) {
    Mred[qt][kh][lq] = mrunA;      Lred[qt][kh][lq] = lfullA;
    Mred[qt][kh][32 + lq] = mrunB; Lred[qt][kh][32 + lq] = lfullB;
  }
  __syncthreads();
  float moA = Mred[qt][kh ^ 1][lq],      loA = Lred[qt][kh ^ 1][lq];
  float moB = Mred[qt][kh ^ 1][32 + lq], loB = Lred[qt][kh ^ 1][32 + lq];
  float mA = fmaxf(mrunA, moA);
  float mB = fmaxf(mrunB, moB);
  float ltotA = lfullA * vexp2(mrunA - mA) + loA * vexp2(moA - mA);
  float ltotB = lfullB * vexp2(mrunB - mB) + loB * vexp2(moB - mB);
  float scA = vexp2(mrunA - mA);
  float scB = vexp2(mrunB - mB);
#pragma unroll
  for (int i = 0; i < 16; ++i) {
    accA0[i] *= scA; accA1[i] *= scA;
    accB0[i] *= scB; accB1[i] *= scB;
  }
  if (kh == 1) {
#pragma unroll
    for (int i = 0; i < 16; ++i) {
      int d = (i & 3) + 8 * (i >> 2) + 4 * hi;
      AccO[qt][d][lq]           = accA0[i];
      AccO[qt][32 + d][lq]      = accA1[i];
      AccO[qt][d][32 + lq]      = accB0[i];
      AccO[qt][32 + d][32 + lq] = accB1[i];
    }
  }
  __syncthreads();
  if (kh == 0) {
#pragma unroll
    for (int i = 0; i < 16; ++i) {
      int d = (i & 3) + 8 * (i >> 2) + 4 * hi;
      AccO[qt][d][lq]           += accA0[i];
      AccO[qt][32 + d][lq]      += accA1[i];
      AccO[qt][d][32 + lq]      += accB0[i];
      AccO[qt][32 + d][32 + lq] += accB1[i];
    }
    // lane l owns q-row qw+l; ltot for it is ltotA (l<32) or ltotB (l>=32),
    // both already resident in the right lanes (value independent of hi).
    float lt = (lane < 32) ? ltotA : ltotB;
    float rl = 1.0f / lt;
    const int b = bh >> 3, h = bh & 7;
    unsigned short* rowp = attn + ((size_t)(b * 2048 + qw + lane)) * 512 + h * 64;
#pragma unroll
    for (int d0 = 0; d0 < 64; d0 += 8) {
      u16x4 o0, o1;
#pragma unroll
      for (int j = 0; j < 4; ++j) {
        o0[j] = f2bf(AccO[qt][d0 + j][lane] * rl);
        o1[j] = f2bf(AccO[qt][d0 + 4 + j][lane] * rl);
      }
      *reinterpret_cast<u16x4*>(rowp + d0) = o0;
      *reinterpret_cast<u16x4*>(rowp + d0 + 4) = o1;
    }
  }
}

// ---------------------------------------------------------------------------
// Output projection (unchanged, verified)
// ---------------------------------------------------------------------------
__global__ __launch_bounds__(256) void out_gemm(
    const unsigned short* __restrict__ A, const float* __restrict__ W,
    const float* __restrict__ bias, float* __restrict__ out)
{
  __shared__ unsigned short Al[128][40];
  __shared__ unsigned short Bl[128][40];
  const int tid = threadIdx.x;
  const int lane = tid & 63;
  const int g = lane >> 4, c = lane & 15;
  const int wave = tid >> 6;
  const int m0 = blockIdx.x * 128, n0 = blockIdx.y * 128;
  const int wm = (wave & 1) * 64, wn = (wave >> 1) * 64;
  f32x4 acc[4][4] = {};

  const int arow = tid >> 2;
  const int acol = (tid & 3) * 8;
  const int srow = tid >> 3;
  const int scol = (tid & 7) * 4;

  for (int k0 = 0; k0 < 512; k0 += 32) {
    __syncthreads();
#pragma unroll
    for (int p = 0; p < 2; ++p) {
      int row = p * 64 + arow;
      short8 av = ld8(&A[(size_t)(m0 + row) * 512 + k0 + acol]);
      *reinterpret_cast<short8*>(&Al[row][acol]) = av;
    }
#pragma unroll
    for (int p = 0; p < 4; ++p) {
      int row = p * 32 + srow;
      f32x4 wv = *reinterpret_cast<const f32x4*>(&W[(size_t)(n0 + row) * 512 + k0 + scol]);
      u16x4 wb = { f2bf(wv[0]), f2bf(wv[1]), f2bf(wv[2]), f2bf(wv[3]) };
      *reinterpret_cast<u16x4*>(&Bl[row][scol]) = wb;
    }
    __syncthreads();
    short8 af[4], bfr[4];
#pragma unroll
    for (int i = 0; i < 4; ++i) {
      af[i]  = ld8(&Al[wm + i * 16 + c][g * 8]);
      bfr[i] = ld8(&Bl[wn + i * 16 + c][g * 8]);
    }
#pragma unroll
    for (int i = 0; i < 4; ++i)
#pragma unroll
      for (int j = 0; j < 4; ++j)
        acc[i][j] = __builtin_amdgcn_mfma_f32_16x16x32_bf16(af[i], bfr[j], acc[i][j], 0, 0, 0);
  }

#pragma unroll
  for (int j = 0; j < 4; ++j) {
    int col = n0 + wn + j * 16 + c;
    float bcol = bias[col];
#pragma unroll
    for (int i = 0; i < 4; ++i)
#pragma unroll
      for (int r = 0; r < 4; ++r) {
        int row = m0 + wm + i * 16 + g * 4 + r;
        out[(size_t)row * 512 + col] = acc[i][j][r] + bcol;
      }
  }
}

extern "C" void kernel_launch(void* const* d_in, const int* in_sizes, int n_in,
                              void* d_out, int out_size, void* d_ws, size_t ws_size,
                              hipStream_t stream)
{
  const float* q  = (const float*)d_in[0];
  const float* k  = (const float*)d_in[1];
  const float* v  = (const float*)d_in[2];
  const float* Wq = (const float*)d_in[3];
  const float* bq = (const float*)d_in[4];
  const float* Wk = (const float*)d_in[5];
  const float* bk = (const float*)d_in[6];
  const float* Wv = (const float*)d_in[7];
  const float* bv = (const float*)d_in[8];
  const float* Wo = (const float*)d_in[9];
  const float* bo = (const float*)d_in[10];
  float* out = (float*)d_out;

  unsigned short* ws = (unsigned short*)d_ws;
  unsigned short* Qh = ws;                              // [32][2048][64] (pre-scaled log2e/8)
  unsigned short* Kh = ws + (size_t)4 * 1024 * 1024;    // [32][2048][64]
  unsigned short* Vt = ws + (size_t)8 * 1024 * 1024;    // [32][64][2048]
  unsigned short* at = ws + (size_t)12 * 1024 * 1024;   // [4][2048][512]

  dim3 blk(256);
  proj3<<<dim3(64, 4, 3), blk, 0, stream>>>(q, k, v, Wq, Wk, Wv, bq, bk, bv, Qh, Kh, Vt);
  flash_attn<<<dim3(16, 32), blk, 0, stream>>>(Qh, Kh, Vt, at);
  out_gemm<<<dim3(64, 4), blk, 0, stream>>>(at, Wo, bo, out);
}